// Round 2
// baseline (1185.995 us; speedup 1.0000x reference)
//
#include <hip/hip_runtime.h>
#include <hip/hip_bf16.h>
#include <math.h>

#define N_NODES 100000
#define N_EDGES 1600000
#define F 128
#define OUT_C 64
#define NUM_CLASSES 40
#define BN_EPS 1e-5f

#define SCAN_T 256
#define SCAN_E 8
#define SCAN_CHUNK (SCAN_T * SCAN_E)

typedef __hip_bfloat16 bf16;

// ---- fp32 param block offsets (element offsets into params[]) ----
#define PW1 0
#define PB1 16384
#define PW2 16512
#define PB2 32896
#define PGAMMA 33024
#define PBETA 33152
#define PMEAN 33280
#define PVAR 33408
#define PCLSW 33536
#define PCLSB 41728
#define PSIMW 41792
#define PSIMB 46912
#define PHOMW 46952
#define PHOMB 47080
#define PENTW 47081
#define PENTB 47209
#define PTOTAL 47210

// ---------------- dtype detection ----------------
// flags[0] = 1 if float inputs are fp32 (else bf16)
// flags[1] = 1 if edge_index is int64 (else int32)
__global__ void detect_kernel(const void* __restrict__ x, const void* __restrict__ ei,
                              int* __restrict__ flags) {
    if (blockIdx.x != 0 || threadIdx.x != 0) return;
    const unsigned* xw = (const unsigned*)x;
    int votes = 0;
    for (int i = 0; i < 64; i++) {
        unsigned w = xw[i];
        unsigned e = (w >> 23) & 0xFFu;
        if (w == 0u || (e >= 90u && e <= 160u)) votes++;
    }
    flags[0] = (votes >= 48) ? 1 : 0;
    const unsigned* ew = (const unsigned*)ei;
    int zero_odd = 0;
    for (int i = 0; i < 64; i++)
        if (ew[2 * i + 1] == 0u) zero_odd++;
    flags[1] = (zero_odd >= 60) ? 1 : 0;
}

// ---------------- generic float convert (bf16 or fp32 -> fp32) ----------------
__global__ void cvt_kernel(const void* __restrict__ src, float* __restrict__ dst, int n,
                           const int* __restrict__ flags) {
    int i = blockIdx.x * blockDim.x + threadIdx.x;
    if (i >= n) return;
    if (flags[0])
        dst[i] = ((const float*)src)[i];
    else
        dst[i] = __bfloat162float(((const bf16*)src)[i]);
}

// ---------------- edge accessors ----------------
__device__ __forceinline__ int load_edge(const int* __restrict__ ei, int which, int i, int i64) {
    // which: 0 = row, 1 = col. int64 layout: element j -> words {2j (low), 2j+1 (high)}
    size_t elem = (size_t)which * N_EDGES + (size_t)i;
    return i64 ? ei[elem * 2] : ei[elem];
}

// ---------------- CSR build ----------------
__global__ void hist_kernel(const int* __restrict__ ei, int* __restrict__ counts,
                            const int* __restrict__ flags) {
    int i = blockIdx.x * blockDim.x + threadIdx.x;
    if (i < N_EDGES) atomicAdd(&counts[load_edge(ei, 1, i, flags[1])], 1);
}

__global__ void scan_a_kernel(const int* __restrict__ counts, int* __restrict__ offsets,
                              int* __restrict__ blkSums, int n) {
    __shared__ int tmp[SCAN_T];
    int base = blockIdx.x * SCAN_CHUNK + threadIdx.x * SCAN_E;
    int v[SCAN_E];
    int tot = 0;
#pragma unroll
    for (int i = 0; i < SCAN_E; i++) {
        int idx = base + i;
        int c = (idx < n) ? counts[idx] : 0;
        v[i] = tot;
        tot += c;
    }
    tmp[threadIdx.x] = tot;
    __syncthreads();
    for (int d = 1; d < SCAN_T; d <<= 1) {
        int t = (threadIdx.x >= d) ? tmp[threadIdx.x - d] : 0;
        __syncthreads();
        tmp[threadIdx.x] += t;
        __syncthreads();
    }
    int ex = tmp[threadIdx.x] - tot;
#pragma unroll
    for (int i = 0; i < SCAN_E; i++) {
        int idx = base + i;
        if (idx < n) offsets[idx] = ex + v[i];
    }
    if (threadIdx.x == SCAN_T - 1) blkSums[blockIdx.x] = tmp[threadIdx.x];
}

__global__ void scan_b_kernel(int* __restrict__ blkSums, int nb) {
    if (threadIdx.x == 0 && blockIdx.x == 0) {
        int run = 0;
        for (int i = 0; i < nb; i++) {
            int t = blkSums[i];
            blkSums[i] = run;
            run += t;
        }
    }
}

__global__ void scan_c_kernel(int* __restrict__ offsets, int* __restrict__ cursor,
                              const int* __restrict__ blkSums, int n) {
    int idx = blockIdx.x * blockDim.x + threadIdx.x;
    if (idx < n) {
        int v = offsets[idx] + blkSums[idx / SCAN_CHUNK];
        offsets[idx] = v;
        cursor[idx] = v;
    }
}

__global__ void fill_kernel(const int* __restrict__ ei, int* __restrict__ cursor,
                            int* __restrict__ srcSorted, const int* __restrict__ flags) {
    int i = blockIdx.x * blockDim.x + threadIdx.x;
    if (i < N_EDGES) {
        int i64 = flags[1];
        int c = load_edge(ei, 1, i, i64);
        int r = load_edge(ei, 0, i, i64);
        int p = atomicAdd(&cursor[c], 1);
        srcSorted[p] = r;
    }
}

__global__ void dinv_kernel(const int* __restrict__ counts, float* __restrict__ dinv, int n) {
    int i = blockIdx.x * blockDim.x + threadIdx.x;
    if (i < n) dinv[i] = rsqrtf((float)(counts[i] + 1));
}

// ---------------- GEMM: C[N x 128] = A[N x 128] * W[128 x 128] ----------------
__global__ void gemm128_kernel(const float* __restrict__ A, const float* __restrict__ W,
                               float* __restrict__ C, int nrows) {
    __shared__ float a[8][F];
    int row0 = blockIdx.x * 8;
    int tid = threadIdx.x;  // 0..127
#pragma unroll
    for (int r = 0; r < 8; r++) {
        int row = row0 + r;
        a[r][tid] = (row < nrows) ? A[row * F + tid] : 0.f;
    }
    __syncthreads();
    float acc[8] = {0.f, 0.f, 0.f, 0.f, 0.f, 0.f, 0.f, 0.f};
    for (int k = 0; k < F; k++) {
        float w = W[k * F + tid];
#pragma unroll
        for (int r = 0; r < 8; r++) acc[r] += a[r][k] * w;
    }
#pragma unroll
    for (int r = 0; r < 8; r++) {
        int row = row0 + r;
        if (row < nrows) C[row * F + tid] = acc[r];
    }
}

// ---------------- Aggregation (one node per 128-thread block) ----------------
__global__ void agg_kernel(const float* __restrict__ hin, float* __restrict__ hout,
                           const int* __restrict__ srcSorted, const int* __restrict__ offsets,
                           const int* __restrict__ counts, const float* __restrict__ dinv,
                           const float* __restrict__ params, int bias_off, int do_bn_relu) {
    int n = blockIdx.x;
    int f = threadIdx.x;
    int off = offsets[n];
    int cnt = counts[n];
    float acc = 0.f;
    for (int j = 0; j < cnt; j++) {
        int s = srcSorted[off + j];
        acc += hin[s * F + f] * dinv[s];
    }
    float dn = dinv[n];
    acc = dn * acc + dn * dn * hin[n * F + f];
    acc += params[bias_off + f];
    if (do_bn_relu) {
        float m = params[PMEAN + f];
        float v = params[PVAR + f];
        float g = params[PGAMMA + f];
        float b = params[PBETA + f];
        acc = (acc - m) * rsqrtf(v + BN_EPS) * g + b;
        acc = fmaxf(acc, 0.f);
    }
    hout[n * F + f] = acc;
}

// ---------------- Heads: one wave (64 lanes) per node ----------------
__global__ void heads_kernel(const float* __restrict__ h, const float* __restrict__ params,
                             void* __restrict__ out, const int* __restrict__ flags) {
    __shared__ float hrow[4][F];
    int isf = flags[0];
    int wave = threadIdx.x >> 6;
    int lane = threadIdx.x & 63;
    int n = blockIdx.x * 4 + wave;
    bool valid = (n < N_NODES);
    if (valid) {
        hrow[wave][lane] = h[n * F + lane];
        hrow[wave][lane + 64] = h[n * F + lane + 64];
    }
    __syncthreads();
    if (!valid) return;
    const float* hr = hrow[wave];

    float acc_c = params[PCLSB + lane];
    float acc_s = (lane < NUM_CLASSES) ? params[PSIMB + lane] : 0.f;
    for (int k = 0; k < F; k++) {
        float hk = hr[k];
        acc_c += hk * params[PCLSW + k * OUT_C + lane];
        if (lane < NUM_CLASSES) acc_s += hk * params[PSIMW + k * NUM_CLASSES + lane];
    }
    float ph = hr[lane] * params[PHOMW + lane] + hr[lane + 64] * params[PHOMW + lane + 64];
    float pe = hr[lane] * params[PENTW + lane] + hr[lane + 64] * params[PENTW + lane + 64];
#pragma unroll
    for (int d = 32; d > 0; d >>= 1) {
        ph += __shfl_xor(ph, d);
        pe += __shfl_xor(pe, d);
    }
    const size_t OFF_SIM = (size_t)N_NODES * OUT_C;
    const size_t OFF_HOM = OFF_SIM + (size_t)N_NODES * NUM_CLASSES;
    const size_t OFF_ENT = OFF_HOM + (size_t)N_NODES;

    float* outf = (float*)out;
    bf16* outb = (bf16*)out;
#define STORE_OUT(idx, v)                         \
    do {                                          \
        if (isf) outf[(idx)] = (v);               \
        else outb[(idx)] = __float2bfloat16(v);   \
    } while (0)

    if (lane == 0) {
        float hv = ph + params[PHOMB];
        float ev = pe + params[PENTB];
        STORE_OUT(OFF_HOM + n, 1.f / (1.f + expf(-hv)));
        STORE_OUT(OFF_ENT + n, 1.f / (1.f + expf(-ev)));
    }
    // log_softmax over 64 cls logits (one per lane)
    float m = acc_c;
#pragma unroll
    for (int d = 32; d > 0; d >>= 1) m = fmaxf(m, __shfl_xor(m, d));
    float ex = expf(acc_c - m);
    float S = ex;
#pragma unroll
    for (int d = 32; d > 0; d >>= 1) S += __shfl_xor(S, d);
    STORE_OUT((size_t)n * OUT_C + lane, acc_c - m - logf(S));

    // softmax over 40 sim logits
    float sv = (lane < NUM_CLASSES) ? acc_s : -INFINITY;
    float ms = sv;
#pragma unroll
    for (int d = 32; d > 0; d >>= 1) ms = fmaxf(ms, __shfl_xor(ms, d));
    float es = (lane < NUM_CLASSES) ? expf(sv - ms) : 0.f;
    float Ss = es;
#pragma unroll
    for (int d = 32; d > 0; d >>= 1) Ss += __shfl_xor(Ss, d);
    if (lane < NUM_CLASSES) STORE_OUT(OFF_SIM + (size_t)n * NUM_CLASSES + lane, es / Ss);
#undef STORE_OUT
}

// ---------------- Launch ----------------
extern "C" void kernel_launch(void* const* d_in, const int* in_sizes, int n_in,
                              void* d_out, int out_size, void* d_ws, size_t ws_size,
                              hipStream_t stream) {
    const void* x = d_in[0];
    const int* ei = (const int*)d_in[1];

    // workspace layout
    char* ws = (char*)d_ws;
    size_t o = 0;
    auto alloc = [&](size_t bytes) {
        size_t r = o;
        o = (o + bytes + 255) & ~(size_t)255;
        return r;
    };
    float* bufA = (float*)(ws + alloc((size_t)N_NODES * F * 4));
    float* bufB = (float*)(ws + alloc((size_t)N_NODES * F * 4));
    float* params = (float*)(ws + alloc((size_t)PTOTAL * 4));
    float* dinv = (float*)(ws + alloc((size_t)N_NODES * 4));
    int* counts = (int*)(ws + alloc((size_t)N_NODES * 4));
    int* offsets = (int*)(ws + alloc((size_t)(N_NODES + 1) * 4));
    int* cursor = (int*)(ws + alloc((size_t)N_NODES * 4));
    int* blkSums = (int*)(ws + alloc(1024));
    int* flags = (int*)(ws + alloc(256));
    int* srcSorted = (int*)(ws + alloc((size_t)N_EDGES * 4));

    const int nScanBlocks = (N_NODES + SCAN_CHUNK - 1) / SCAN_CHUNK;  // 49

    detect_kernel<<<1, 64, 0, stream>>>(x, ei, flags);
    hipMemsetAsync(counts, 0, (size_t)N_NODES * 4, stream);

    // convert x into bufB (canonical fp32)
    cvt_kernel<<<(N_NODES * F + 255) / 256, 256, 0, stream>>>(x, bufB, N_NODES * F, flags);
    // convert params
    struct {
        int src_idx;
        int dst_off;
        int n;
    } segs[13] = {
        {2, PW1, 16384},   {3, PB1, 128},    {4, PW2, 16384},  {5, PB2, 128},
        {6, PGAMMA, 128},  {7, PBETA, 128},  {8, PMEAN, 128},  {9, PVAR, 128},
        {10, PCLSW, 8192}, {11, PCLSB, 64},  {12, PSIMW, 5120},{13, PSIMB, 40},
        {14, PHOMW, 128},
    };
    for (int s = 0; s < 13; s++)
        cvt_kernel<<<(segs[s].n + 255) / 256, 256, 0, stream>>>(d_in[segs[s].src_idx],
                                                                params + segs[s].dst_off,
                                                                segs[s].n, flags);
    cvt_kernel<<<1, 64, 0, stream>>>(d_in[15], params + PHOMB, 1, flags);
    cvt_kernel<<<1, 128, 0, stream>>>(d_in[16], params + PENTW, 128, flags);
    cvt_kernel<<<1, 64, 0, stream>>>(d_in[17], params + PENTB, 1, flags);

    // CSR build
    hist_kernel<<<(N_EDGES + 255) / 256, 256, 0, stream>>>(ei, counts, flags);
    scan_a_kernel<<<nScanBlocks, SCAN_T, 0, stream>>>(counts, offsets, blkSums, N_NODES);
    scan_b_kernel<<<1, 64, 0, stream>>>(blkSums, nScanBlocks);
    scan_c_kernel<<<(N_NODES + 255) / 256, 256, 0, stream>>>(offsets, cursor, blkSums, N_NODES);
    fill_kernel<<<(N_EDGES + 255) / 256, 256, 0, stream>>>(ei, cursor, srcSorted, flags);
    dinv_kernel<<<(N_NODES + 255) / 256, 256, 0, stream>>>(counts, dinv, N_NODES);

    // layer 1: x(bufB) @ w1 -> bufA; agg+BN+ReLU -> bufB
    gemm128_kernel<<<(N_NODES + 7) / 8, F, 0, stream>>>(bufB, params + PW1, bufA, N_NODES);
    agg_kernel<<<N_NODES, F, 0, stream>>>(bufA, bufB, srcSorted, offsets, counts, dinv,
                                          params, PB1, 1);
    // layer 2
    gemm128_kernel<<<(N_NODES + 7) / 8, F, 0, stream>>>(bufB, params + PW2, bufA, N_NODES);
    agg_kernel<<<N_NODES, F, 0, stream>>>(bufA, bufB, srcSorted, offsets, counts, dinv,
                                          params, PB2, 0);
    // heads
    heads_kernel<<<(N_NODES + 3) / 4, 256, 0, stream>>>(bufB, params, d_out, flags);
}

// Round 3
// 860.805 us; speedup vs baseline: 1.3778x; 1.3778x over previous
//
#include <hip/hip_runtime.h>
#include <hip/hip_bf16.h>
#include <math.h>

#define N_NODES 100000
#define N_EDGES 1600000
#define F 128
#define OUT_C 64
#define NUM_CLASSES 40
#define BN_EPS 1e-5f

#define SCAN_T 256
#define SCAN_E 8
#define SCAN_CHUNK (SCAN_T * SCAN_E)

typedef __hip_bfloat16 bf16;

// ---- fp32 param block offsets (element offsets into params[]) ----
#define PW1 0
#define PB1 16384
#define PW2 16512
#define PB2 32896
#define PGAMMA 33024
#define PBETA 33152
#define PMEAN 33280
#define PVAR 33408
#define PCLSW 33536
#define PCLSB 41728
#define PSIMW 41792
#define PSIMB 46912
#define PHOMW 46952
#define PHOMB 47080
#define PENTW 47081
#define PENTB 47209
// fused layer2+heads weights: Wfuse[128 x 128] (cols 0-63 cls, 64-103 sim, 104 hom, 105 ent, rest 0)
#define PFW 47232
#define PFB 63616
#define PTOTAL 63744

// ---------------- dtype detection ----------------
// flags[0] = 1 if float inputs are fp32 (else bf16); flags[1] = 1 if edge_index int64
__global__ void detect_kernel(const void* __restrict__ x, const void* __restrict__ ei,
                              int* __restrict__ flags) {
    if (blockIdx.x != 0 || threadIdx.x != 0) return;
    const unsigned* xw = (const unsigned*)x;
    int votes = 0;
    for (int i = 0; i < 64; i++) {
        unsigned w = xw[i];
        unsigned e = (w >> 23) & 0xFFu;
        if (w == 0u || (e >= 90u && e <= 160u)) votes++;
    }
    flags[0] = (votes >= 48) ? 1 : 0;
    const unsigned* ew = (const unsigned*)ei;
    int zero_odd = 0;
    for (int i = 0; i < 64; i++)
        if (ew[2 * i + 1] == 0u) zero_odd++;
    flags[1] = (zero_odd >= 60) ? 1 : 0;
}

// ---------------- generic float convert (bf16 or fp32 -> fp32) ----------------
__global__ void cvt_kernel(const void* __restrict__ src, float* __restrict__ dst, int n,
                           const int* __restrict__ flags) {
    int i = blockIdx.x * blockDim.x + threadIdx.x;
    if (i >= n) return;
    if (flags[0])
        dst[i] = ((const float*)src)[i];
    else
        dst[i] = __bfloat162float(((const bf16*)src)[i]);
}

// ---------------- edge accessors ----------------
__device__ __forceinline__ int load_edge(const int* __restrict__ ei, int which, int i, int i64) {
    size_t elem = (size_t)which * N_EDGES + (size_t)i;
    return i64 ? ei[elem * 2] : ei[elem];
}

// ---------------- CSR build ----------------
__global__ void hist_kernel(const int* __restrict__ ei, int* __restrict__ counts,
                            const int* __restrict__ flags) {
    int i = blockIdx.x * blockDim.x + threadIdx.x;
    if (i < N_EDGES) atomicAdd(&counts[load_edge(ei, 1, i, flags[1])], 1);
}

__global__ void scan_a_kernel(const int* __restrict__ counts, int* __restrict__ offsets,
                              int* __restrict__ blkSums, int n) {
    __shared__ int tmp[SCAN_T];
    int base = blockIdx.x * SCAN_CHUNK + threadIdx.x * SCAN_E;
    int v[SCAN_E];
    int tot = 0;
#pragma unroll
    for (int i = 0; i < SCAN_E; i++) {
        int idx = base + i;
        int c = (idx < n) ? counts[idx] : 0;
        v[i] = tot;
        tot += c;
    }
    tmp[threadIdx.x] = tot;
    __syncthreads();
    for (int d = 1; d < SCAN_T; d <<= 1) {
        int t = (threadIdx.x >= d) ? tmp[threadIdx.x - d] : 0;
        __syncthreads();
        tmp[threadIdx.x] += t;
        __syncthreads();
    }
    int ex = tmp[threadIdx.x] - tot;
#pragma unroll
    for (int i = 0; i < SCAN_E; i++) {
        int idx = base + i;
        if (idx < n) offsets[idx] = ex + v[i];
    }
    if (threadIdx.x == SCAN_T - 1) blkSums[blockIdx.x] = tmp[threadIdx.x];
}

__global__ void scan_b_kernel(int* __restrict__ blkSums, int nb) {
    if (threadIdx.x == 0 && blockIdx.x == 0) {
        int run = 0;
        for (int i = 0; i < nb; i++) {
            int t = blkSums[i];
            blkSums[i] = run;
            run += t;
        }
    }
}

__global__ void scan_c_kernel(int* __restrict__ offsets, int* __restrict__ cursor,
                              const int* __restrict__ blkSums, int n) {
    int idx = blockIdx.x * blockDim.x + threadIdx.x;
    if (idx < n) {
        int v = offsets[idx] + blkSums[idx / SCAN_CHUNK];
        offsets[idx] = v;
        cursor[idx] = v;
    }
}

__global__ void fill_kernel(const int* __restrict__ ei, int* __restrict__ cursor,
                            int* __restrict__ srcSorted, const int* __restrict__ flags) {
    int i = blockIdx.x * blockDim.x + threadIdx.x;
    if (i < N_EDGES) {
        int i64 = flags[1];
        int c = load_edge(ei, 1, i, i64);
        int r = load_edge(ei, 0, i, i64);
        int p = atomicAdd(&cursor[c], 1);
        srcSorted[p] = r;
    }
}

__global__ void dinv_kernel(const int* __restrict__ counts, float* __restrict__ dinv, int n) {
    int i = blockIdx.x * blockDim.x + threadIdx.x;
    if (i < n) dinv[i] = rsqrtf((float)(counts[i] + 1));
}

// ---------------- fused W2 @ [cls|sim|hom|ent] precompute ----------------
__device__ __forceinline__ float headw(const float* __restrict__ p, int j, int c) {
    if (c < OUT_C) return p[PCLSW + j * OUT_C + c];
    if (c < OUT_C + NUM_CLASSES) return p[PSIMW + j * NUM_CLASSES + (c - OUT_C)];
    if (c == 104) return p[PHOMW + j];
    if (c == 105) return p[PENTW + j];
    return 0.f;
}

__global__ void fusew_kernel(float* __restrict__ params) {
    int idx = blockIdx.x * 256 + threadIdx.x;  // 64 blocks -> 16384 threads
    int k = idx >> 7;
    int c = idx & 127;
    float s = 0.f;
    for (int j = 0; j < 128; j++) s += params[PW2 + k * 128 + j] * headw(params, j, c);
    params[PFW + k * 128 + c] = s;
    if (k == 0) {
        float b = 0.f;
        for (int j = 0; j < 128; j++) b += params[PB2 + j] * headw(params, j, c);
        if (c < OUT_C) b += params[PCLSB + c];
        else if (c < OUT_C + NUM_CLASSES) b += params[PSIMB + c - OUT_C];
        else if (c == 104) b += params[PHOMB];
        else if (c == 105) b += params[PENTB];
        params[PFB + c] = b;
    }
}

// ---------------- GEMM: C[nrows x 128] = A[nrows x 128] @ W[128 x 128] + bias (+BN+ReLU) ----
// 64-row tile, 256 threads, per-thread 4 rows x 8 cols. A^T staged in LDS; W from global (L1).
#define ATPITCH 68  // 64 rows + 4 pad (multiple of 4 keeps float4 alignment)

__global__ __launch_bounds__(256) void gemm_kernel(const float* __restrict__ A,
                                                   const float* __restrict__ Wg,
                                                   float* __restrict__ C,
                                                   const float* __restrict__ params,
                                                   int bias_off, int bn_relu, int nrows) {
    __shared__ float At[128 * ATPITCH];  // ~34.8 KB
    int row0 = blockIdx.x * 64;
    int t = threadIdx.x;
    int rows_here = nrows - row0;
    if (rows_here > 64) rows_here = 64;
#pragma unroll
    for (int it = 0; it < 8; it++) {
        int idx4 = it * 256 + t;       // 0..2047 float4 units
        int r = idx4 >> 5;             // 0..63
        int c4 = (idx4 & 31) << 2;     // 0,4,..,124
        float4 v = make_float4(0.f, 0.f, 0.f, 0.f);
        if (r < rows_here) v = *(const float4*)&A[(size_t)(row0 + r) * 128 + c4];
        At[(c4 + 0) * ATPITCH + r] = v.x;
        At[(c4 + 1) * ATPITCH + r] = v.y;
        At[(c4 + 2) * ATPITCH + r] = v.z;
        At[(c4 + 3) * ATPITCH + r] = v.w;
    }
    __syncthreads();

    int rg = (t & 15) << 2;  // 0..60
    int cg = (t >> 4) << 3;  // 0..120
    float acc[4][8];
#pragma unroll
    for (int i = 0; i < 4; i++)
#pragma unroll
        for (int j = 0; j < 8; j++) acc[i][j] = 0.f;

#pragma unroll 4
    for (int k = 0; k < 128; k++) {
        float4 a = *(const float4*)&At[k * ATPITCH + rg];
        float4 w0 = *(const float4*)&Wg[k * 128 + cg];
        float4 w1 = *(const float4*)&Wg[k * 128 + cg + 4];
        float aa[4] = {a.x, a.y, a.z, a.w};
        float ww[8] = {w0.x, w0.y, w0.z, w0.w, w1.x, w1.y, w1.z, w1.w};
#pragma unroll
        for (int i = 0; i < 4; i++)
#pragma unroll
            for (int j = 0; j < 8; j++) acc[i][j] += aa[i] * ww[j];
    }

    float bias[8], scale[8], shift[8];
#pragma unroll
    for (int j = 0; j < 8; j++) {
        int c = cg + j;
        bias[j] = params[bias_off + c];
        if (bn_relu) {
            float s = rsqrtf(params[PVAR + c] + BN_EPS) * params[PGAMMA + c];
            scale[j] = s;
            shift[j] = params[PBETA + c] - params[PMEAN + c] * s;
        }
    }
#pragma unroll
    for (int i = 0; i < 4; i++) {
        int r = row0 + rg + i;
        if (r < nrows) {
            float o[8];
#pragma unroll
            for (int j = 0; j < 8; j++) {
                float v = acc[i][j] + bias[j];
                if (bn_relu) v = fmaxf(v * scale[j] + shift[j], 0.f);
                o[j] = v;
            }
            *(float4*)&C[(size_t)r * 128 + cg] = make_float4(o[0], o[1], o[2], o[3]);
            *(float4*)&C[(size_t)r * 128 + cg + 4] = make_float4(o[4], o[5], o[6], o[7]);
        }
    }
}

// ---------------- Aggregation: out[n] = dinv[n]*sum_{e} h[s]*dinv[s] + dinv[n]^2*h[n] ------
// One wave handles 2 nodes (32 lanes each, float4 per lane = full 128-f row per half-wave).
__global__ __launch_bounds__(256) void agg_kernel(const float* __restrict__ hin,
                                                  float* __restrict__ hout,
                                                  const int* __restrict__ srcSorted,
                                                  const int* __restrict__ offsets,
                                                  const int* __restrict__ counts,
                                                  const float* __restrict__ dinv) {
    int wave = threadIdx.x >> 6;
    int lane = threadIdx.x & 63;
    int half = lane >> 5;
    int hl = lane & 31;
    int n = blockIdx.x * 8 + wave * 2 + half;
    if (n >= N_NODES) return;
    int off = offsets[n];
    int cnt = counts[n];
    const float4* hin4 = (const float4*)hin;
    float4 acc = make_float4(0.f, 0.f, 0.f, 0.f);
    int j = 0;
    for (; j + 2 <= cnt; j += 2) {
        int s0 = srcSorted[off + j];
        int s1 = srcSorted[off + j + 1];
        float d0 = dinv[s0];
        float d1 = dinv[s1];
        float4 v0 = hin4[(size_t)s0 * 32 + hl];
        float4 v1 = hin4[(size_t)s1 * 32 + hl];
        acc.x += v0.x * d0 + v1.x * d1;
        acc.y += v0.y * d0 + v1.y * d1;
        acc.z += v0.z * d0 + v1.z * d1;
        acc.w += v0.w * d0 + v1.w * d1;
    }
    if (j < cnt) {
        int s0 = srcSorted[off + j];
        float d0 = dinv[s0];
        float4 v0 = hin4[(size_t)s0 * 32 + hl];
        acc.x += v0.x * d0;
        acc.y += v0.y * d0;
        acc.z += v0.z * d0;
        acc.w += v0.w * d0;
    }
    float dn = dinv[n];
    float4 self = hin4[(size_t)n * 32 + hl];
    float4 o;
    o.x = dn * acc.x + dn * dn * self.x;
    o.y = dn * acc.y + dn * dn * self.y;
    o.z = dn * acc.z + dn * dn * self.z;
    o.w = dn * acc.w + dn * dn * self.w;
    ((float4*)hout)[(size_t)n * 32 + hl] = o;
}

// ---------------- Postprocess: logits[N x 128] -> outputs ----------------
__global__ __launch_bounds__(256) void post_kernel(const float* __restrict__ L,
                                                   void* __restrict__ out,
                                                   const int* __restrict__ flags) {
    int isf = flags[0];
    int wave = threadIdx.x >> 6;
    int lane = threadIdx.x & 63;
    int n = blockIdx.x * 4 + wave;
    if (n >= N_NODES) return;
    const float* row = L + (size_t)n * 128;
    float a = row[lane];
    float sv = (lane < NUM_CLASSES) ? row[OUT_C + lane] : -INFINITY;

    const size_t OFF_SIM = (size_t)N_NODES * OUT_C;
    const size_t OFF_HOM = OFF_SIM + (size_t)N_NODES * NUM_CLASSES;
    const size_t OFF_ENT = OFF_HOM + (size_t)N_NODES;
    float* outf = (float*)out;
    bf16* outb = (bf16*)out;
#define STORE_OUT(idx, v)                        \
    do {                                         \
        if (isf) outf[(idx)] = (v);              \
        else outb[(idx)] = __float2bfloat16(v);  \
    } while (0)

    if (lane == 0) {
        STORE_OUT(OFF_HOM + n, 1.f / (1.f + expf(-row[104])));
        STORE_OUT(OFF_ENT + n, 1.f / (1.f + expf(-row[105])));
    }
    // log_softmax over 64 cls logits
    float m = a;
#pragma unroll
    for (int d = 32; d > 0; d >>= 1) m = fmaxf(m, __shfl_xor(m, d));
    float ex = expf(a - m);
    float S = ex;
#pragma unroll
    for (int d = 32; d > 0; d >>= 1) S += __shfl_xor(S, d);
    STORE_OUT((size_t)n * OUT_C + lane, a - m - logf(S));
    // softmax over 40 sim logits
    float ms = sv;
#pragma unroll
    for (int d = 32; d > 0; d >>= 1) ms = fmaxf(ms, __shfl_xor(ms, d));
    float es = (lane < NUM_CLASSES) ? expf(sv - ms) : 0.f;
    float Ss = es;
#pragma unroll
    for (int d = 32; d > 0; d >>= 1) Ss += __shfl_xor(Ss, d);
    if (lane < NUM_CLASSES) STORE_OUT(OFF_SIM + (size_t)n * NUM_CLASSES + lane, es / Ss);
#undef STORE_OUT
}

// ---------------- Launch ----------------
extern "C" void kernel_launch(void* const* d_in, const int* in_sizes, int n_in,
                              void* d_out, int out_size, void* d_ws, size_t ws_size,
                              hipStream_t stream) {
    const void* x = d_in[0];
    const int* ei = (const int*)d_in[1];

    char* ws = (char*)d_ws;
    size_t o = 0;
    auto alloc = [&](size_t bytes) {
        size_t r = o;
        o = (o + bytes + 255) & ~(size_t)255;
        return r;
    };
    float* SA = (float*)(ws + alloc((size_t)N_NODES * F * 4));
    float* SB = (float*)(ws + alloc((size_t)N_NODES * F * 4));
    float* params = (float*)(ws + alloc((size_t)PTOTAL * 4));
    float* dinv = (float*)(ws + alloc((size_t)N_NODES * 4));
    int* counts = (int*)(ws + alloc((size_t)N_NODES * 4));
    int* offsets = (int*)(ws + alloc((size_t)(N_NODES + 1) * 4));
    int* cursor = (int*)(ws + alloc((size_t)N_NODES * 4));
    int* blkSums = (int*)(ws + alloc(1024));
    int* flags = (int*)(ws + alloc(256));
    int* srcSorted = (int*)(ws + alloc((size_t)N_EDGES * 4));

    const int nScanBlocks = (N_NODES + SCAN_CHUNK - 1) / SCAN_CHUNK;

    detect_kernel<<<1, 64, 0, stream>>>(x, ei, flags);
    hipMemsetAsync(counts, 0, (size_t)N_NODES * 4, stream);

    // canonical fp32: x -> SA
    cvt_kernel<<<(N_NODES * F + 255) / 256, 256, 0, stream>>>(x, SA, N_NODES * F, flags);
    // params -> fp32 block
    struct { int src_idx, dst_off, n; } segs[13] = {
        {2, PW1, 16384},   {3, PB1, 128},    {4, PW2, 16384},  {5, PB2, 128},
        {6, PGAMMA, 128},  {7, PBETA, 128},  {8, PMEAN, 128},  {9, PVAR, 128},
        {10, PCLSW, 8192}, {11, PCLSB, 64},  {12, PSIMW, 5120},{13, PSIMB, 40},
        {14, PHOMW, 128},
    };
    for (int s = 0; s < 13; s++)
        cvt_kernel<<<(segs[s].n + 255) / 256, 256, 0, stream>>>(d_in[segs[s].src_idx],
                                                                params + segs[s].dst_off,
                                                                segs[s].n, flags);
    cvt_kernel<<<1, 64, 0, stream>>>(d_in[15], params + PHOMB, 1, flags);
    cvt_kernel<<<1, 128, 0, stream>>>(d_in[16], params + PENTW, 128, flags);
    cvt_kernel<<<1, 64, 0, stream>>>(d_in[17], params + PENTB, 1, flags);

    // CSR build
    hist_kernel<<<(N_EDGES + 255) / 256, 256, 0, stream>>>(ei, counts, flags);
    scan_a_kernel<<<nScanBlocks, SCAN_T, 0, stream>>>(counts, offsets, blkSums, N_NODES);
    scan_b_kernel<<<1, 64, 0, stream>>>(blkSums, nScanBlocks);
    scan_c_kernel<<<(N_NODES + 255) / 256, 256, 0, stream>>>(offsets, cursor, blkSums, N_NODES);
    fill_kernel<<<(N_EDGES + 255) / 256, 256, 0, stream>>>(ei, cursor, srcSorted, flags);
    dinv_kernel<<<(N_NODES + 255) / 256, 256, 0, stream>>>(counts, dinv, N_NODES);

    // fused layer2+head weights (needs params only)
    fusew_kernel<<<64, 256, 0, stream>>>(params);

    const int aggGrid = (N_NODES + 7) / 8;
    const int gemmGrid = (N_NODES + 63) / 64;

    // layer 1 (reordered): g1 = A_hat x ; h1 = ReLU(BN(g1 @ W1 + b1))
    agg_kernel<<<aggGrid, 256, 0, stream>>>(SA, SB, srcSorted, offsets, counts, dinv);
    gemm_kernel<<<gemmGrid, 256, 0, stream>>>(SB, params + PW1, SA, params, PB1, 1, N_NODES);
    // layer 2 + heads fused: g2 = A_hat h1 ; logits = g2 @ Wfuse + bfuse
    agg_kernel<<<aggGrid, 256, 0, stream>>>(SA, SB, srcSorted, offsets, counts, dinv);
    gemm_kernel<<<gemmGrid, 256, 0, stream>>>(SB, params + PFW, SA, params, PFB, 0, N_NODES);
    // postprocess
    post_kernel<<<(N_NODES + 3) / 4, 256, 0, stream>>>(SA, d_out, flags);
}